// Round 12
// baseline (87.362 us; speedup 1.0000x reference)
//
#include <hip/hip_runtime.h>
#include <hip/hip_fp16.h>
#include <math.h>

#define D_DET 512
#define N_ANG 180
#define S_IMG 512
#define NPIX  (S_IMG * S_IMG)
#define T_MAX 63                 // ramp tap truncation

typedef _Float16 half2v __attribute__((ext_vector_type(2)));

__device__ __constant__ float kPI = 3.14159265358979323846f;

__device__ __forceinline__ half2v pack_weights(float a, float b) {
    return __builtin_bit_cast(half2v, __builtin_amdgcn_cvt_pkrtz(a, b));
}

// ---------------------------------------------------------------------------
// Stage 1: ramp filter (R5 verbatim — known-good, ~2 us).
//   xf[d] = 0.5*r[d] + sum_{t odd,<=63} h(t)*(r[d-t]+r[d+t]), h(t)=-2/(pi t)^2
// Output word (a*512+d)*2+bc = packed fp16 (xf[d], xf[d+1]), xf[512]=0.
// ---------------------------------------------------------------------------
__global__ __launch_bounds__(512) void ramp_filter_kernel(
    const float* __restrict__ x, unsigned* __restrict__ xfh) {
    __shared__ float rp[640];            // [0,64)=0, [64,576)=row, [576,640)=0
    __shared__ float xf[D_DET + 1];

    const int a  = blockIdx.x >> 1;
    const int bc = blockIdx.x & 1;
    const int d  = threadIdx.x;

    if (d < 64)   rp[d] = 0.0f;
    if (d >= 448) rp[d + 128] = 0.0f;
    rp[64 + d] = x[(bc * D_DET + d) * N_ANG + a];
    if (d == 0) xf[D_DET] = 0.0f;
    __syncthreads();

    constexpr float PI_ = 3.14159265358979323846f;
    const float* rm = &rp[64 + d];
    float acc = 0.5f * rm[0];
    #pragma unroll
    for (int k = 0; k < (T_MAX + 1) / 2; ++k) {
        const int   t = 2 * k + 1;
        const float h = -2.0f / (PI_ * PI_ * (float)(t * t));   // literal
        acc = fmaf(rm[-t] + rm[t], h, acc);
    }
    xf[d] = acc;
    __syncthreads();

    const unsigned lo = __half_as_ushort(__float2half_rn(xf[d]));
    const unsigned hi = __half_as_ushort(__float2half_rn(xf[d + 1]));
    xfh[(a * D_DET + d) * 2 + bc] = (hi << 16) | lo;
}

// ---------------------------------------------------------------------------
// Stage 2: backprojection, leanest loop variant.
// Block = 16x16 pixels (waves = compact 8x8 patches). Thread = 1 pixel,
// both images: one 8B uint2 gather + 2 fdot2 per angle.
// Per-block LDS table bycs[il][a] = (cos*255.5, 255.5 - y_il*sin*255.5)
// folds the per-iter y*sin fma away: loop = ds_read_b64 + fma + med3 +
// floor + sub + sub + cvt_pk + cvt_i32 + addr + load + 2 fdot2.
// Grid: 1024 blocks x 256 threads = 16 waves/CU.
// LAUNCHED 3x THIS ROUND (decomposition experiment: T3 - T1 = 2B).
// ---------------------------------------------------------------------------
__global__ __launch_bounds__(256) void backproj_kernel(
    const uint2* __restrict__ xfh, float* __restrict__ out) {
    __shared__ float2 csA[N_ANG];        // (c*255.5, s*255.5)
    __shared__ float2 bycs[16 * 256];    // [il][a] padded to 256

    const int tid = threadIdx.x;
    const int bi  = blockIdx.x >> 5;     // 32 i-tiles of 16
    const int bj  = blockIdx.x & 31;     // 32 j-tiles of 16
    const int i0  = bi << 4;

    if (tid < N_ANG) {
        float th = (float)tid * (kPI / 180.0f);
        float s, c;
        sincosf(th, &s, &c);
        csA[tid] = make_float2(c * 255.5f, s * 255.5f);
    }
    __syncthreads();
    if (tid < N_ANG) {
        float2 cs = csA[tid];
        #pragma unroll
        for (int il = 0; il < 16; ++il) {
            float y = (float)(i0 + il) * (2.0f / 511.0f) - 1.0f;
            bycs[(il << 8) + tid] = make_float2(cs.x, fmaf(-y, cs.y, 255.5f));
        }
    }
    __syncthreads();

    const int wave = tid >> 6;
    const int lane = tid & 63;
    const int il   = ((wave >> 1) << 3) + (lane >> 3);
    const int j    = (bj << 4) + ((wave & 1) << 3) + (lane & 7);
    const int i    = i0 + il;

    const float xP = (float)j * (2.0f / 511.0f) - 1.0f;
    const float yP = (float)i * (2.0f / 511.0f) - 1.0f;
    const float m  = xP * xP + yP * yP;
    const int  p   = i * S_IMG + j;

    if (!__any(m <= 1.0f)) {             // whole 8x8 patch outside circle
        out[p]        = 0.0f;
        out[NPIX + p] = 0.0f;
        return;
    }

    const float2* __restrict__ bc = &bycs[il << 8];
    float a0 = 0.0f, a1 = 0.0f;
    #pragma unroll 4
    for (int a = 0; a < N_ANG; ++a) {
        float2 t  = bc[a];                                        // ds_read_b64
        float pc  = fminf(fmaxf(fmaf(xP, t.x, t.y), 0.0f), 511.0f); // med3
        float fi  = floorf(pc);
        float w   = pc - fi;
        half2v hw = pack_weights(1.0f - w, w);
        uint2  g  = xfh[(a << 9) + (int)fi];
        a0 = __builtin_amdgcn_fdot2(hw, __builtin_bit_cast(half2v, g.x), a0, false);
        a1 = __builtin_amdgcn_fdot2(hw, __builtin_bit_cast(half2v, g.y), a1, false);
    }

    const float msk = (m <= 1.0f) ? (kPI / (2.0f * (float)N_ANG)) : 0.0f;
    out[p]        = a0 * msk;
    out[NPIX + p] = a1 * msk;
}

// ---------------------------------------------------------------------------
extern "C" void kernel_launch(void* const* d_in, const int* in_sizes, int n_in,
                              void* d_out, int out_size, void* d_ws, size_t ws_size,
                              hipStream_t stream) {
    const float* x   = (const float*)d_in[0];
    float*       out = (float*)d_out;
    unsigned*    xfh = (unsigned*)d_ws;  // 180*512*8 = 737,280 bytes

    ramp_filter_kernel<<<N_ANG * 2, 512, 0, stream>>>(x, xfh);
    // Decomposition experiment: backproj is idempotent (same table -> same
    // output values), so launching 3x is deterministic and lets the timing
    // difference vs a 1x run isolate B = backproj duration exactly.
    backproj_kernel<<<1024, 256, 0, stream>>>((const uint2*)xfh, out);
    backproj_kernel<<<1024, 256, 0, stream>>>((const uint2*)xfh, out);
    backproj_kernel<<<1024, 256, 0, stream>>>((const uint2*)xfh, out);
}

// Round 13
// 33.971 us; speedup vs baseline: 2.5716x; 2.5716x over previous
//
#include <hip/hip_runtime.h>
#include <hip/hip_fp16.h>
#include <math.h>

#define D_DET 512
#define N_ANG 180
#define S_IMG 512
#define NPIX  (S_IMG * S_IMG)
#define T_MAX 63                 // ramp tap truncation

typedef _Float16 half2v __attribute__((ext_vector_type(2)));

__device__ __constant__ float kPI = 3.14159265358979323846f;

__device__ __forceinline__ half2v pack_weights(float a, float b) {
    return __builtin_bit_cast(half2v, __builtin_amdgcn_cvt_pkrtz(a, b));
}

// ---------------------------------------------------------------------------
// Stage 1: ramp filter, truncated symmetric convolution, angle-quad blocks.
//   xf[d] = 0.5*r[d] + sum_{t odd,<=63} h(t)*(r[d-t]+r[d+t]), h(t)=-2/(pi t)^2
// Block = (bc, 4 consecutive angles): input loads are 16B float4 over the
// contiguous angle axis (4x fewer scattered requests than per-angle blocks).
// Each thread convolves its detector cell for all 4 staged rows.
// Grid: 90 blocks x 512 threads.
// Output word (a*512+d)*2+bc = packed fp16 (xf[d], xf[d+1]), xf[512]=0.
// ---------------------------------------------------------------------------
__global__ __launch_bounds__(512) void ramp_filter_kernel(
    const float* __restrict__ x, unsigned* __restrict__ xfh) {
    __shared__ float rp[4][640];         // per row: [0,64)=0, [64,576), [576,640)=0
    __shared__ float xf[4][D_DET + 1];

    const int blk = blockIdx.x;
    const int bc  = blk >> 6 >= 0 ? (blk / 45) : 0;      // 0..1
    const int a0  = (blk % 45) * 4;
    const int d   = threadIdx.x;

    // Stage 4 rows; input is contiguous over angles -> one float4 per lane.
    float4 q = *(const float4*)(x + (bc * D_DET + d) * N_ANG + a0);
    rp[0][64 + d] = q.x;
    rp[1][64 + d] = q.y;
    rp[2][64 + d] = q.z;
    rp[3][64 + d] = q.w;
    if (d < 64) {
        #pragma unroll
        for (int r = 0; r < 4; ++r) { rp[r][d] = 0.0f; rp[r][576 + d] = 0.0f; }
    }
    if (d < 4) xf[d][D_DET] = 0.0f;
    __syncthreads();

    constexpr float PI_ = 3.14159265358979323846f;
    #pragma unroll
    for (int r = 0; r < 4; ++r) {
        const float* rm = &rp[r][64 + d];
        float acc = 0.5f * rm[0];
        #pragma unroll
        for (int k = 0; k < (T_MAX + 1) / 2; ++k) {
            const int   t = 2 * k + 1;
            const float h = -2.0f / (PI_ * PI_ * (float)(t * t));   // literal
            acc = fmaf(rm[-t] + rm[t], h, acc);
        }
        xf[r][d] = acc;
    }
    __syncthreads();

    #pragma unroll
    for (int r = 0; r < 4; ++r) {
        const unsigned lo = __half_as_ushort(__float2half_rn(xf[r][d]));
        const unsigned hi = __half_as_ushort(__float2half_rn(xf[r][d + 1]));
        xfh[((a0 + r) * D_DET + d) * 2 + bc] = (hi << 16) | lo;
    }
}

// ---------------------------------------------------------------------------
// Stage 2: backprojection (R8 structure verbatim — fastest measured).
// Wave = compact 8x8 pixel patch; thread = 1 pixel, both images:
// one 8B uint2 gather + cvt_pkrtz + 2 fdot2 per angle.
// Block = 16x16 pixels (4 waves). Grid 1024 x 256. Tiny LDS.
// ---------------------------------------------------------------------------
__global__ __launch_bounds__(256) void backproj_kernel(
    const uint2* __restrict__ xfh, float* __restrict__ out) {
    __shared__ float2 trig[N_ANG];       // (cos*255.5, sin*255.5)
    const int tid = threadIdx.x;
    if (tid < N_ANG) {
        float th = (float)tid * (kPI / 180.0f);
        float s, c;
        sincosf(th, &s, &c);
        trig[tid] = make_float2(c * 255.5f, s * 255.5f);
    }
    __syncthreads();

    const int bi   = blockIdx.x >> 5;    // 32 i-tiles of 16
    const int bj   = blockIdx.x & 31;    // 32 j-tiles of 16
    const int wave = tid >> 6;
    const int lane = tid & 63;
    const int i = (bi << 4) + ((wave >> 1) << 3) + (lane >> 3);
    const int j = (bj << 4) + ((wave & 1) << 3) + (lane & 7);

    const float xP = (float)j * (2.0f / 511.0f) - 1.0f;
    const float yP = (float)i * (2.0f / 511.0f) - 1.0f;
    const float m  = xP * xP + yP * yP;
    const int  p   = i * S_IMG + j;

    if (!__any(m <= 1.0f)) {             // whole 8x8 patch outside circle
        out[p]        = 0.0f;
        out[NPIX + p] = 0.0f;
        return;
    }

    float a0 = 0.0f, a1 = 0.0f;
    #pragma unroll 4
    for (int a = 0; a < N_ANG; ++a) {
        float2 t  = trig[a];
        float pc  = fminf(fmaxf(fmaf(xP, t.x, fmaf(yP, -t.y, 255.5f)), 0.0f), 511.0f);
        float fi  = floorf(pc);
        float w   = pc - fi;
        half2v hw = pack_weights(1.0f - w, w);
        uint2  g  = xfh[(a << 9) + (int)fi];
        a0 = __builtin_amdgcn_fdot2(hw, __builtin_bit_cast(half2v, g.x), a0, false);
        a1 = __builtin_amdgcn_fdot2(hw, __builtin_bit_cast(half2v, g.y), a1, false);
    }

    const float msk = (m <= 1.0f) ? (kPI / (2.0f * (float)N_ANG)) : 0.0f;
    out[p]        = a0 * msk;
    out[NPIX + p] = a1 * msk;
}

// ---------------------------------------------------------------------------
extern "C" void kernel_launch(void* const* d_in, const int* in_sizes, int n_in,
                              void* d_out, int out_size, void* d_ws, size_t ws_size,
                              hipStream_t stream) {
    const float* x   = (const float*)d_in[0];
    float*       out = (float*)d_out;
    unsigned*    xfh = (unsigned*)d_ws;  // 180*512*8 = 737,280 bytes

    ramp_filter_kernel<<<90, 512, 0, stream>>>(x, xfh);
    backproj_kernel<<<1024, 256, 0, stream>>>((const uint2*)xfh, out);
}